// Round 1
// baseline (496.893 us; speedup 1.0000x reference)
//
#include <hip/hip_runtime.h>
#include <stdint.h>

#define M_DIM 8192
#define N_DIM 4096
#define K_DIM 4096

typedef int v4i __attribute__((ext_vector_type(4)));

// ---------------------------------------------------------------------------
// async global->LDS copy, 16 B per lane (wave-uniform LDS base + lane*16)
// ---------------------------------------------------------------------------
typedef __attribute__((address_space(1))) const void gas_void;
typedef __attribute__((address_space(3))) void las_void;

__device__ __forceinline__ void async_copy16(const uint8_t* g, uint8_t* l) {
    __builtin_amdgcn_global_load_lds((gas_void*)g, (las_void*)l, 16, 0, 0);
}

__device__ __forceinline__ int quant1(float x, float scale) {
    // Matches jnp.clip(jnp.round(x/scale), -127, 127): IEEE fp32 divide +
    // round-to-nearest-even (v_rndne), then clamp.
    float q = __builtin_rintf(x / scale);
    q = fminf(127.0f, fmaxf(-127.0f, q));
    return (int)q;
}

__device__ __forceinline__ uint32_t pack4(int q0, int q1, int q2, int q3) {
    return (uint32_t)(q0 & 255) | ((uint32_t)(q1 & 255) << 8) |
           ((uint32_t)(q2 & 255) << 16) | ((uint32_t)(q3 & 255) << 24);
}

// ---------------------------------------------------------------------------
// Kernel 1: per-row absmax + quantize lhs -> qlhs [M][K] int8 row-major
// One block per row; 256 threads x 16 elements (4x float4).
// ---------------------------------------------------------------------------
__global__ __launch_bounds__(256) void quant_lhs_kernel(
    const float* __restrict__ lhs, uint8_t* __restrict__ qlhs,
    float* __restrict__ lhs_scale) {
    const int row = blockIdx.x;
    const int tid = threadIdx.x;
    const float4* src = (const float4*)(lhs + (size_t)row * K_DIM);

    float4 v[4];
    float m = 0.0f;
#pragma unroll
    for (int i = 0; i < 4; ++i) {
        v[i] = src[tid + i * 256];
        m = fmaxf(m, fmaxf(fmaxf(fabsf(v[i].x), fabsf(v[i].y)),
                           fmaxf(fabsf(v[i].z), fabsf(v[i].w))));
    }
#pragma unroll
    for (int off = 32; off > 0; off >>= 1)
        m = fmaxf(m, __shfl_down(m, off, 64));

    __shared__ float wmax[4];
    if ((tid & 63) == 0) wmax[tid >> 6] = m;
    __syncthreads();
    const float mm = fmaxf(fmaxf(wmax[0], wmax[1]), fmaxf(wmax[2], wmax[3]));
    const float scale = (mm == 0.0f) ? 1.0f : mm / 127.0f;
    if (tid == 0) lhs_scale[row] = scale;

    uint32_t* dst = (uint32_t*)(qlhs + (size_t)row * K_DIM);
#pragma unroll
    for (int i = 0; i < 4; ++i) {
        dst[tid + i * 256] = pack4(quant1(v[i].x, scale), quant1(v[i].y, scale),
                                   quant1(v[i].z, scale), quant1(v[i].w, scale));
    }
}

// ---------------------------------------------------------------------------
// Kernel 2a: rhs column absmax (partial over 128-row stripes, atomicMax on
// float bits -- valid since |x| >= 0 makes the uint compare monotonic).
// ---------------------------------------------------------------------------
__global__ __launch_bounds__(256) void rhs_max_kernel(
    const float* __restrict__ rhs, uint32_t* __restrict__ maxbits) {
    const int c = blockIdx.x * 256 + threadIdx.x;
    const int r0 = blockIdx.y * 128;
    float m = 0.0f;
    for (int r = 0; r < 128; ++r)
        m = fmaxf(m, fabsf(rhs[(size_t)(r0 + r) * N_DIM + c]));
    atomicMax(&maxbits[c], __float_as_uint(m));
}

// Kernel 2b: maxbits -> rhs_scale
__global__ __launch_bounds__(256) void rhs_scale_kernel(
    const uint32_t* __restrict__ maxbits, float* __restrict__ rhs_scale) {
    const int c = blockIdx.x * 256 + threadIdx.x;
    const float m = __uint_as_float(maxbits[c]);
    rhs_scale[c] = (m == 0.0f) ? 1.0f : m / 127.0f;
}

// ---------------------------------------------------------------------------
// Kernel 2c: quantize + transpose rhs -> qrhsT [N][K] int8 row-major.
// Reads coalesced along n; each thread owns one column n and writes 16-byte
// k-runs (uint4) to its own qrhsT row.
// Grid: (N/256, K/256). Each thread does 256 elements.
// ---------------------------------------------------------------------------
__global__ __launch_bounds__(256) void quant_rhs_t_kernel(
    const float* __restrict__ rhs, const float* __restrict__ rhs_scale,
    uint8_t* __restrict__ qrhsT) {
    const int n = blockIdx.x * 256 + threadIdx.x;
    const float scale = rhs_scale[n];
    const int kbase = blockIdx.y * 256;

    for (int c16 = 0; c16 < 16; ++c16) {
        const int k0 = kbase + c16 * 16;
        uint32_t p[4];
#pragma unroll
        for (int g = 0; g < 4; ++g) {
            int q[4];
#pragma unroll
            for (int j = 0; j < 4; ++j) {
                const float x = rhs[(size_t)(k0 + g * 4 + j) * N_DIM + n];
                q[j] = quant1(x, scale);
            }
            p[g] = pack4(q[0], q[1], q[2], q[3]);
        }
        uint4 u;
        u.x = p[0]; u.y = p[1]; u.z = p[2]; u.w = p[3];
        *(uint4*)(qrhsT + (size_t)n * K_DIM + k0) = u;
    }
}

// ---------------------------------------------------------------------------
// Kernel 3: int8 GEMM, m97 structure. 128x128 block tile, BK=64, 256 threads
// (4 waves, each computing a 64x64 sub-tile as 4x4 MFMA 16x16x64 tiles).
// A staged from qlhs [M][K]; B staged from qrhsT [N][K] (both k-contiguous).
// Epilogue dequant: out = acc * lhs_scale[m] * rhs_scale[n].
// ---------------------------------------------------------------------------
__global__ __launch_bounds__(256) void gemm_i8_kernel(
    const uint8_t* __restrict__ qlhs, const uint8_t* __restrict__ qrhsT,
    const float* __restrict__ lhs_scale, const float* __restrict__ rhs_scale,
    float* __restrict__ out) {
    __shared__ __align__(16) uint8_t As[128 * 64];  // [row m][k byte], stride 64
    __shared__ __align__(16) uint8_t Bs[128 * 64];  // [row n][k byte], stride 64

    const int tid = threadIdx.x;
    const int wave = tid >> 6;
    const int lane = tid & 63;

    const int bm = blockIdx.y * 128;
    const int bn = blockIdx.x * 128;

    // --- staging addressing: wave w covers LDS bytes [w*2048, w*2048+2048),
    // i.e. rows w*32 .. w*32+31. Two 1024 B instructions (16 rows each).
    const int srow = wave * 32 + (lane >> 2);
    const int scol = (lane & 3) * 16;
    const uint8_t* ga = qlhs + (size_t)(bm + srow) * K_DIM + scol;
    const uint8_t* gb = qrhsT + (size_t)(bn + srow) * K_DIM + scol;
    uint8_t* la = As + wave * 2048 + lane * 16;
    uint8_t* lb = Bs + wave * 2048 + lane * 16;
    const size_t rowstep16 = (size_t)16 * K_DIM;  // +16 rows in global

    // --- fragment addressing (A-frag: m=lane&15, k=(lane>>4)*16+j; B same)
    const int wm = (wave >> 1) * 64;
    const int wn = (wave & 1) * 64;
    const int fra = (wm + (lane & 15)) * 64 + (lane >> 4) * 16;
    const int frb = (wn + (lane & 15)) * 64 + (lane >> 4) * 16;

    v4i acc[4][4] = {};

    for (int k0 = 0; k0 < K_DIM; k0 += 64) {
        async_copy16(ga, la);
        async_copy16(ga + rowstep16, la + 1024);
        async_copy16(gb, lb);
        async_copy16(gb + rowstep16, lb + 1024);
        ga += 64;
        gb += 64;
        __syncthreads();  // compiler emits vmcnt(0) drain before barrier

        v4i a[4], b[4];
#pragma unroll
        for (int i = 0; i < 4; ++i) a[i] = *(const v4i*)(As + fra + i * 1024);
#pragma unroll
        for (int i = 0; i < 4; ++i) b[i] = *(const v4i*)(Bs + frb + i * 1024);
#pragma unroll
        for (int mi = 0; mi < 4; ++mi)
#pragma unroll
            for (int ni = 0; ni < 4; ++ni)
                acc[mi][ni] = __builtin_amdgcn_mfma_i32_16x16x64_i8(
                    a[mi], b[ni], acc[mi][ni], 0, 0, 0);
        __syncthreads();
    }

    // --- epilogue: C/D layout col=lane&15, row=(lane>>4)*4+reg
    const int r0 = bm + wm + (lane >> 4) * 4;
    const int c0 = bn + wn + (lane & 15);
#pragma unroll
    for (int mi = 0; mi < 4; ++mi) {
        float ls[4];
#pragma unroll
        for (int r = 0; r < 4; ++r) ls[r] = lhs_scale[r0 + mi * 16 + r];
#pragma unroll
        for (int ni = 0; ni < 4; ++ni) {
            const int col = c0 + ni * 16;
            const float rs = rhs_scale[col];
            float* o = out + (size_t)(r0 + mi * 16) * N_DIM + col;
#pragma unroll
            for (int r = 0; r < 4; ++r)
                o[(size_t)r * N_DIM] = (float)acc[mi][ni][r] * ls[r] * rs;
        }
    }
}

// ---------------------------------------------------------------------------
// Workspace layout (bytes):
//   qlhs   [0, 33554432)
//   qrhsT  [33554432, 50331648)
//   lhs_scale (float[8192])   @ 50331648
//   rhs_scale (float[4096])   @ 50364416
//   maxbits   (uint32[4096])  @ 50380800
// Total: 50397184 B
// ---------------------------------------------------------------------------
extern "C" void kernel_launch(void* const* d_in, const int* in_sizes, int n_in,
                              void* d_out, int out_size, void* d_ws,
                              size_t ws_size, hipStream_t stream) {
    const float* lhs = (const float*)d_in[0];
    const float* rhs = (const float*)d_in[1];
    float* out = (float*)d_out;

    uint8_t* ws = (uint8_t*)d_ws;
    uint8_t* qlhs = ws;
    uint8_t* qrhsT = ws + 33554432u;
    float* lhs_scale = (float*)(ws + 50331648u);
    float* rhs_scale = (float*)(ws + 50364416u);
    uint32_t* maxbits = (uint32_t*)(ws + 50380800u);

    hipMemsetAsync(maxbits, 0, N_DIM * sizeof(uint32_t), stream);

    quant_lhs_kernel<<<M_DIM, 256, 0, stream>>>(lhs, qlhs, lhs_scale);
    rhs_max_kernel<<<dim3(N_DIM / 256, 32), 256, 0, stream>>>(rhs, maxbits);
    rhs_scale_kernel<<<N_DIM / 256, 256, 0, stream>>>(maxbits, rhs_scale);
    quant_rhs_t_kernel<<<dim3(N_DIM / 256, K_DIM / 256), 256, 0, stream>>>(
        rhs, rhs_scale, qrhsT);
    gemm_i8_kernel<<<dim3(N_DIM / 128, M_DIM / 128), 256, 0, stream>>>(
        qlhs, qrhsT, lhs_scale, rhs_scale, out);
}

// Round 2
// 440.462 us; speedup vs baseline: 1.1281x; 1.1281x over previous
//
#include <hip/hip_runtime.h>
#include <stdint.h>

#define M_DIM 8192
#define N_DIM 4096
#define K_DIM 4096

typedef int v4i __attribute__((ext_vector_type(4)));

// ---------------------------------------------------------------------------
// async global->LDS copy, 16 B per lane (wave-uniform LDS base + lane*16)
// ---------------------------------------------------------------------------
typedef __attribute__((address_space(1))) const void gas_void;
typedef __attribute__((address_space(3))) void las_void;

__device__ __forceinline__ void async_copy16(const uint8_t* g, uint8_t* l) {
    __builtin_amdgcn_global_load_lds((gas_void*)g, (las_void*)l, 16, 0, 0);
}

__device__ __forceinline__ int quant1(float x, float scale) {
    // Matches jnp.clip(jnp.round(x/scale), -127, 127): IEEE fp32 divide +
    // round-to-nearest-even (v_rndne), then clamp.
    float q = __builtin_rintf(x / scale);
    q = fminf(127.0f, fmaxf(-127.0f, q));
    return (int)q;
}

__device__ __forceinline__ uint32_t pack4(int q0, int q1, int q2, int q3) {
    return (uint32_t)(q0 & 255) | ((uint32_t)(q1 & 255) << 8) |
           ((uint32_t)(q2 & 255) << 16) | ((uint32_t)(q3 & 255) << 24);
}

// ---------------------------------------------------------------------------
// Kernel 1: per-row absmax + quantize lhs -> qlhs [M][K] int8 row-major
// ---------------------------------------------------------------------------
__global__ __launch_bounds__(256) void quant_lhs_kernel(
    const float* __restrict__ lhs, uint8_t* __restrict__ qlhs,
    float* __restrict__ lhs_scale) {
    const int row = blockIdx.x;
    const int tid = threadIdx.x;
    const float4* src = (const float4*)(lhs + (size_t)row * K_DIM);

    float4 v[4];
    float m = 0.0f;
#pragma unroll
    for (int i = 0; i < 4; ++i) {
        v[i] = src[tid + i * 256];
        m = fmaxf(m, fmaxf(fmaxf(fabsf(v[i].x), fabsf(v[i].y)),
                           fmaxf(fabsf(v[i].z), fabsf(v[i].w))));
    }
#pragma unroll
    for (int off = 32; off > 0; off >>= 1)
        m = fmaxf(m, __shfl_down(m, off, 64));

    __shared__ float wmax[4];
    if ((tid & 63) == 0) wmax[tid >> 6] = m;
    __syncthreads();
    const float mm = fmaxf(fmaxf(wmax[0], wmax[1]), fmaxf(wmax[2], wmax[3]));
    const float scale = (mm == 0.0f) ? 1.0f : mm / 127.0f;
    if (tid == 0) lhs_scale[row] = scale;

    uint32_t* dst = (uint32_t*)(qlhs + (size_t)row * K_DIM);
#pragma unroll
    for (int i = 0; i < 4; ++i) {
        dst[tid + i * 256] = pack4(quant1(v[i].x, scale), quant1(v[i].y, scale),
                                   quant1(v[i].z, scale), quant1(v[i].w, scale));
    }
}

// ---------------------------------------------------------------------------
// Kernel 2a: rhs column absmax. 32 rows per block (grid.y = 128) for better
// latency hiding; atomicMax on float bits (monotone for non-negative floats).
// ---------------------------------------------------------------------------
__global__ __launch_bounds__(256) void rhs_max_kernel(
    const float* __restrict__ rhs, uint32_t* __restrict__ maxbits) {
    const int c = blockIdx.x * 256 + threadIdx.x;
    const int r0 = blockIdx.y * 32;
    float m = 0.0f;
#pragma unroll
    for (int r = 0; r < 32; ++r)
        m = fmaxf(m, fabsf(rhs[(size_t)(r0 + r) * N_DIM + c]));
    atomicMax(&maxbits[c], __float_as_uint(m));
}

// Kernel 2b: maxbits -> rhs_scale
__global__ __launch_bounds__(256) void rhs_scale_kernel(
    const uint32_t* __restrict__ maxbits, float* __restrict__ rhs_scale) {
    const int c = blockIdx.x * 256 + threadIdx.x;
    const float m = __uint_as_float(maxbits[c]);
    rhs_scale[c] = (m == 0.0f) ? 1.0f : m / 127.0f;
}

// ---------------------------------------------------------------------------
// Kernel 2c: quantize + transpose rhs -> qrhsT [N][K] int8 row-major.
// LDS-tiled: 128(k) x 64(n) tile per block, 4x4 register micro-transpose,
// LDS rows padded to 132 B for conflict-free column writes, 128B-coalesced
// global stores (8 lanes x 16B per qrhsT row).
// Grid: (N/64, K/128) = (64, 32).
// ---------------------------------------------------------------------------
__global__ __launch_bounds__(256) void quant_rhs_t_kernel(
    const float* __restrict__ rhs, const float* __restrict__ rhs_scale,
    uint8_t* __restrict__ qrhsT) {
    __shared__ __align__(16) uint8_t tile[64 * 132];  // [n][k + 4B pad]
    const int nbase = blockIdx.x * 64;
    const int kbase = blockIdx.y * 128;
    const int tid = threadIdx.x;

    const int n0 = (tid & 15) * 4;
    const float s0 = rhs_scale[nbase + n0];
    const float s1 = rhs_scale[nbase + n0 + 1];
    const float s2 = rhs_scale[nbase + n0 + 2];
    const float s3 = rhs_scale[nbase + n0 + 3];

#pragma unroll
    for (int p = 0; p < 2; ++p) {
        const int k0 = (tid >> 4) * 4 + p * 64;
        int q[4][4];  // [i = k offset][j = n offset]
#pragma unroll
        for (int i = 0; i < 4; ++i) {
            const float4 v = *(const float4*)(
                rhs + (size_t)(kbase + k0 + i) * N_DIM + nbase + n0);
            q[i][0] = quant1(v.x, s0);
            q[i][1] = quant1(v.y, s1);
            q[i][2] = quant1(v.z, s2);
            q[i][3] = quant1(v.w, s3);
        }
#pragma unroll
        for (int j = 0; j < 4; ++j) {
            // 4 consecutive k for column n0+j; banks (n+kg) mod 32 -> 2-way max
            *(uint32_t*)(tile + (n0 + j) * 132 + k0) =
                pack4(q[0][j], q[1][j], q[2][j], q[3][j]);
        }
    }
    __syncthreads();

#pragma unroll
    for (int p = 0; p < 2; ++p) {
        const int c = tid + p * 256;
        const int n = c >> 3;
        const int g = c & 7;
        uint32_t d[4];
#pragma unroll
        for (int w = 0; w < 4; ++w)
            d[w] = *(const uint32_t*)(tile + n * 132 + g * 16 + w * 4);
        uint4 u;
        u.x = d[0]; u.y = d[1]; u.z = d[2]; u.w = d[3];
        *(uint4*)(qrhsT + (size_t)(nbase + n) * K_DIM + kbase + g * 16) = u;
    }
}

// ---------------------------------------------------------------------------
// Kernel 3: int8 GEMM, m97 structure + XOR-swizzled LDS to kill the 8-way
// bank conflicts on stride-64B fragment reads. Chunk (row, g) of 16 bytes is
// stored at g_lds = g ^ ((row>>1)&3); fragment reads then hit all 8
// bank-groups with exactly 2 lanes each (2-way = free, m136).
// ---------------------------------------------------------------------------
__global__ __launch_bounds__(256) void gemm_i8_kernel(
    const uint8_t* __restrict__ qlhs, const uint8_t* __restrict__ qrhsT,
    const float* __restrict__ lhs_scale, const float* __restrict__ rhs_scale,
    float* __restrict__ out) {
    __shared__ __align__(16) uint8_t As[128 * 64];  // [m][k], swizzled
    __shared__ __align__(16) uint8_t Bs[128 * 64];  // [n][k], swizzled

    const int tid = threadIdx.x;
    const int wave = tid >> 6;
    const int lane = tid & 63;

    const int bm = blockIdx.y * 128;
    const int bn = blockIdx.x * 128;

    // staging: lane -> (row = wave*32 + lane>>2, g_lds = lane&3);
    // source chunk g_src = g_lds ^ ((row>>1)&3) = (lane&3) ^ ((lane>>3)&3).
    // Invariant under row += 16, so the second (+16 rows) load reuses scol.
    const int srow = wave * 32 + (lane >> 2);
    const int scol = ((lane & 3) ^ ((lane >> 3) & 3)) * 16;
    const uint8_t* ga = qlhs + (size_t)(bm + srow) * K_DIM + scol;
    const uint8_t* gb = qrhsT + (size_t)(bn + srow) * K_DIM + scol;
    uint8_t* la = As + wave * 2048 + lane * 16;
    uint8_t* lb = Bs + wave * 2048 + lane * 16;
    const size_t rowstep16 = (size_t)16 * K_DIM;

    // fragments: want chunk (row = wm + lane&15 (+16i), g = lane>>4);
    // stored at g_lds = g ^ ((row>>1)&3) = (lane>>4) ^ ((lane>>1)&3)
    // (invariant under +16i and +wm since those are multiples of 8 in row>>1).
    const int wm = (wave >> 1) * 64;
    const int wn = (wave & 1) * 64;
    const int fra =
        (wm + (lane & 15)) * 64 + (((lane >> 4) ^ ((lane >> 1) & 3)) * 16);
    const int frb =
        (wn + (lane & 15)) * 64 + (((lane >> 4) ^ ((lane >> 1) & 3)) * 16);

    v4i acc[4][4] = {};

    for (int k0 = 0; k0 < K_DIM; k0 += 64) {
        async_copy16(ga, la);
        async_copy16(ga + rowstep16, la + 1024);
        async_copy16(gb, lb);
        async_copy16(gb + rowstep16, lb + 1024);
        ga += 64;
        gb += 64;
        __syncthreads();

        v4i a[4], b[4];
#pragma unroll
        for (int i = 0; i < 4; ++i) a[i] = *(const v4i*)(As + fra + i * 1024);
#pragma unroll
        for (int i = 0; i < 4; ++i) b[i] = *(const v4i*)(Bs + frb + i * 1024);
#pragma unroll
        for (int mi = 0; mi < 4; ++mi)
#pragma unroll
            for (int ni = 0; ni < 4; ++ni)
                acc[mi][ni] = __builtin_amdgcn_mfma_i32_16x16x64_i8(
                    a[mi], b[ni], acc[mi][ni], 0, 0, 0);
        __syncthreads();
    }

    // epilogue: C/D layout col=lane&15, row=(lane>>4)*4+reg
    const int r0 = bm + wm + (lane >> 4) * 4;
    const int c0 = bn + wn + (lane & 15);
#pragma unroll
    for (int mi = 0; mi < 4; ++mi) {
        float ls[4];
#pragma unroll
        for (int r = 0; r < 4; ++r) ls[r] = lhs_scale[r0 + mi * 16 + r];
#pragma unroll
        for (int ni = 0; ni < 4; ++ni) {
            const int col = c0 + ni * 16;
            const float rs = rhs_scale[col];
            float* o = out + (size_t)(r0 + mi * 16) * N_DIM + col;
#pragma unroll
            for (int r = 0; r < 4; ++r)
                o[(size_t)r * N_DIM] = (float)acc[mi][ni][r] * ls[r] * rs;
        }
    }
}

// ---------------------------------------------------------------------------
// Workspace layout (bytes):
//   qlhs   [0, 33554432)
//   qrhsT  [33554432, 50331648)
//   lhs_scale (float[8192])   @ 50331648
//   rhs_scale (float[4096])   @ 50364416
//   maxbits   (uint32[4096])  @ 50380800
// ---------------------------------------------------------------------------
extern "C" void kernel_launch(void* const* d_in, const int* in_sizes, int n_in,
                              void* d_out, int out_size, void* d_ws,
                              size_t ws_size, hipStream_t stream) {
    const float* lhs = (const float*)d_in[0];
    const float* rhs = (const float*)d_in[1];
    float* out = (float*)d_out;

    uint8_t* ws = (uint8_t*)d_ws;
    uint8_t* qlhs = ws;
    uint8_t* qrhsT = ws + 33554432u;
    float* lhs_scale = (float*)(ws + 50331648u);
    float* rhs_scale = (float*)(ws + 50364416u);
    uint32_t* maxbits = (uint32_t*)(ws + 50380800u);

    hipMemsetAsync(maxbits, 0, N_DIM * sizeof(uint32_t), stream);

    quant_lhs_kernel<<<M_DIM, 256, 0, stream>>>(lhs, qlhs, lhs_scale);
    rhs_max_kernel<<<dim3(N_DIM / 256, 128), 256, 0, stream>>>(rhs, maxbits);
    rhs_scale_kernel<<<N_DIM / 256, 256, 0, stream>>>(maxbits, rhs_scale);
    quant_rhs_t_kernel<<<dim3(N_DIM / 64, K_DIM / 128), 256, 0, stream>>>(
        rhs, rhs_scale, qrhsT);
    gemm_i8_kernel<<<dim3(N_DIM / 128, M_DIM / 128), 256, 0, stream>>>(
        qlhs, qrhsT, lhs_scale, rhs_scale, out);
}